// Round 16
// baseline (5753.315 us; speedup 1.0000x reference)
//
#include <hip/hip_runtime.h>
#include <hip/hip_bf16.h>
#include <cstdint>

#define DEV __device__ __forceinline__

typedef __attribute__((ext_vector_type(8))) short bf16x8;
typedef __attribute__((ext_vector_type(4))) float f32x4;
typedef unsigned short u16;
typedef unsigned int u32;

// ---- problem constants ----
constexpr int BN_   = 32;
constexpr int PP    = 256;
constexpr int PL_   = 16;
constexpr int CT    = 4;
constexpr int LL    = 260;
constexpr int DD    = 1152;
constexpr int HH    = 16;
constexpr int HDIM  = 72;
constexpr int DEPTH_= 12;
constexpr int TD    = 3456;
constexpr int MLPD_ = 4608;
constexpr int MREAL = BN_*LL;   // 8320
constexpr int MPAD  = 8448;     // 66*128 = 33*256
constexpr int LP    = 288;
constexpr int HDP   = 96;
constexpr int HDV   = 80;
constexpr float SCALE_ = 0.11785113019775793f;

// weight arena offsets (elements)
constexpr size_t OP_ = (size_t)TD*DD;
constexpr size_t OF1 = OP_ + (size_t)DD*DD;
constexpr size_t OF2 = OF1 + (size_t)MLPD_*DD;
constexpr size_t ARENA_ELEMS = OF2 + (size_t)1280*MLPD_;

DEV u16 f2bf(float f){
    union{float f; u32 i;} c; c.f = f;
    u32 u = c.i;
    u32 r = (u + 0x7fffu + ((u>>16)&1u)) >> 16;
    return (u16)r;
}
DEV float bf2f(u32 u){ union{u32 i; float f;} c; c.i = u<<16; return c.f; }

DEV float wave_sum64(float v){
    #pragma unroll
    for (int off=32; off; off>>=1) v += __shfl_xor(v, off);
    return v;
}
DEV float group16_sum(float v){
    #pragma unroll
    for (int off=8; off; off>>=1) v += __shfl_xor(v, off);
    return v;
}
DEV float gelu_f(float x){
    float u = 0.7978845608028654f * (x + 0.044715f * x*x*x);
    return x / (1.f + __expf(-2.f * u));
}

// ---- timestep embedding ----
__global__ void temb1_kernel(const float* __restrict__ t, const float* __restrict__ tw1,
                             const float* __restrict__ tb1, float* __restrict__ e1)
{
    int n = blockIdx.y, j = blockIdx.x*128 + threadIdx.x;
    float tv = t[n];
    float acc = tb1[j];
    const float k = 0.07195578415606394f;
    for (int i = 0; i < 128; ++i) {
        float f = __expf(-k * (float)i);
        float a = tv * f;
        float sa = sinf(a), ca = cosf(a);
        acc += ca * tw1[(size_t)i*DD + j] + sa * tw1[(size_t)(i+128)*DD + j];
    }
    e1[(size_t)n*DD + j] = acc / (1.f + __expf(-acc));
}

__global__ void temb2_kernel(const float* __restrict__ e1, const float* __restrict__ tw2,
                             const float* __restrict__ tb2, float* __restrict__ te)
{
    int n = blockIdx.y, j = blockIdx.x*128 + threadIdx.x;
    float acc = tb2[j];
    const float* er = e1 + (size_t)n*DD;
    for (int kk = 0; kk < DD; ++kk)
        acc += er[kk] * tw2[(size_t)kk*DD + j];
    te[(size_t)n*DD + j] = acc;
}

// ---- token assembly ----
__global__ void assemble_kernel(const float* __restrict__ x, const int* __restrict__ y,
                                const float* __restrict__ xw, const float* __restrict__ xb,
                                const float* __restrict__ ytab, const float* __restrict__ pos,
                                const float* __restrict__ cpos, const float* __restrict__ te,
                                float* __restrict__ tokf)
{
    int m = blockIdx.x;
    if (m >= MREAL) {
        for (int d = threadIdx.x; d < DD; d += 256) tokf[(size_t)m*DD + d] = 0.f;
        return;
    }
    int n = m / LL, l = m % LL;
    if (l < CT) {
        int cls = y[n];
        const float* yt = ytab + (size_t)cls*(CT*DD) + (size_t)l*DD;
        const float* cp = cpos + (size_t)l*DD;
        const float* tm = te + (size_t)n*DD;
        for (int d = threadIdx.x; d < DD; d += 256)
            tokf[(size_t)m*DD + d] = yt[d] + cp[d] + tm[d];
    } else {
        int p = l - CT;
        const float* xr = x + (size_t)(n*PP + p)*PL_;
        float xv[16];
        #pragma unroll
        for (int i=0;i<16;i++) xv[i] = xr[i];
        const float* pr = pos + (size_t)p*DD;
        for (int d = threadIdx.x; d < DD; d += 256) {
            float acc = xb[d] + pr[d];
            #pragma unroll
            for (int i=0;i<16;i++) acc += xv[i] * xw[(size_t)i*DD + d];
            tokf[(size_t)m*DD + d] = acc;
        }
    }
}

// ---- merged: convT (blocks 0..3887, layer-0 weights) + ln1 (blocks 3888..) ----
__global__ void convln_kernel(const float* __restrict__ qkvw, const float* __restrict__ pw,
                              const float* __restrict__ f1w, const float* __restrict__ f2w,
                              u16* __restrict__ arena,
                              const float* __restrict__ src, const float* __restrict__ g,
                              const float* __restrict__ b, u16* __restrict__ dst)
{
    __shared__ float tile[64][65];
    int id = blockIdx.x;
    if (id >= 3888) {
        int lane = threadIdx.x & 63, w = threadIdx.x >> 6;
        int m = (id - 3888)*4 + w;
        const float* row = src + (size_t)m * DD;
        float4 v[5];
        float s = 0.f, ss = 0.f;
        #pragma unroll
        for (int i=0;i<5;i++) {
            int idx = i*64 + lane;
            if (idx < 288) {
                v[i] = ((const float4*)row)[idx];
                s  += v[i].x + v[i].y + v[i].z + v[i].w;
                ss += v[i].x*v[i].x + v[i].y*v[i].y + v[i].z*v[i].z + v[i].w*v[i].w;
            }
        }
        s = wave_sum64(s); ss = wave_sum64(ss);
        float mean = s * (1.f/DD);
        float var  = ss * (1.f/DD) - mean*mean;
        float rs   = rsqrtf(var + 1e-5f);
        u16* orow = dst + (size_t)m*DD;
        #pragma unroll
        for (int i=0;i<5;i++) {
            int idx = i*64 + lane;
            if (idx < 288) {
                int c0 = idx*4;
                float4 gg = ((const float4*)g)[idx];
                float4 bb = ((const float4*)b)[idx];
                ushort4 o;
                o.x = f2bf((v[i].x-mean)*rs*gg.x + bb.x);
                o.y = f2bf((v[i].y-mean)*rs*gg.y + bb.y);
                o.z = f2bf((v[i].z-mean)*rs*gg.z + bb.z);
                o.w = f2bf((v[i].w-mean)*rs*gg.w + bb.w);
                *(ushort4*)(orow + c0) = o;
            }
        }
        return;
    }
    const float* W; u16* WT; int K, Nw, t0;
    if (id < 972)        { W = qkvw; WT = arena;        K = DD;    Nw = TD;    t0 = id; }
    else if (id < 1296)  { W = pw;   WT = arena + OP_;  K = DD;    Nw = DD;    t0 = id - 972; }
    else if (id < 2592)  { W = f1w;  WT = arena + OF1;  K = DD;    Nw = MLPD_; t0 = id - 1296; }
    else                 { W = f2w;  WT = arena + OF2;  K = MLPD_; Nw = DD;    t0 = id - 2592; }
    int nx = Nw >> 6;
    int nb = (t0 % nx) * 64, kb = (t0 / nx) * 64;
    int tx = threadIdx.x & 63, ty = threadIdx.x >> 6;
    #pragma unroll
    for (int r=0;r<16;r++)
        tile[r*4 + ty][tx] = W[(size_t)(kb + r*4 + ty)*Nw + nb + tx];
    __syncthreads();
    int j = threadIdx.x & 63, i2 = threadIdx.x >> 6;
    #pragma unroll
    for (int r=0;r<16;r++) {
        int n = i2 + r*4;
        WT[(size_t)(nb + n)*K + kb + j] = f2bf(tile[j][n]);
    }
}

// ---- LayerNorm (standalone) ----
__global__ void ln_kernel(const float* __restrict__ src, const float* __restrict__ g,
                          const float* __restrict__ b, u16* __restrict__ dst)
{
    int lane = threadIdx.x & 63, w = threadIdx.x >> 6;
    int m = blockIdx.x*4 + w;
    const float* row = src + (size_t)m * DD;
    float4 v[5];
    float s = 0.f, ss = 0.f;
    #pragma unroll
    for (int i=0;i<5;i++) {
        int idx = i*64 + lane;
        if (idx < 288) {
            v[i] = ((const float4*)row)[idx];
            s  += v[i].x + v[i].y + v[i].z + v[i].w;
            ss += v[i].x*v[i].x + v[i].y*v[i].y + v[i].z*v[i].z + v[i].w*v[i].w;
        }
    }
    s = wave_sum64(s); ss = wave_sum64(ss);
    float mean = s * (1.f/DD);
    float var  = ss * (1.f/DD) - mean*mean;
    float rs   = rsqrtf(var + 1e-5f);
    u16* orow = dst + (size_t)m*DD;
    #pragma unroll
    for (int i=0;i<5;i++) {
        int idx = i*64 + lane;
        if (idx < 288) {
            int c0 = idx*4;
            float4 gg = ((const float4*)g)[idx];
            float4 bb = ((const float4*)b)[idx];
            ushort4 o;
            o.x = f2bf((v[i].x-mean)*rs*gg.x + bb.x);
            o.y = f2bf((v[i].y-mean)*rs*gg.y + bb.y);
            o.z = f2bf((v[i].z-mean)*rs*gg.z + bb.z);
            o.w = f2bf((v[i].w-mean)*rs*gg.w + bb.w);
            *(ushort4*)(orow + c0) = o;
        }
    }
}

// ---- m97-structure GEMM: 128x128, BK=64, single-buffer (proj/fc2) ----
// EPI: 0 = bf16 store, 1 = gelu(x+bias)->bf16, 2 = x + bias + tokf -> tokf fp32
template<int EPI>
__global__ __launch_bounds__(256, 4)
void gemm97_kernel(const u16* __restrict__ A, const u16* __restrict__ BT,
                   int K, int Nreal, u16* __restrict__ outb, float* __restrict__ outf,
                   const float* __restrict__ bias)
{
    __shared__ u16 As[128][64];
    __shared__ u16 Bs[128][64];
    const int tid = threadIdx.x;
    const int lane = tid & 63, wv = tid >> 6;
    const int wq = wv >> 1, wp = wv & 1;
    const int l15 = lane & 15, g4 = lane >> 4;

    const int id = blockIdx.x + gridDim.x * blockIdx.y;
    const int total = gridDim.x * gridDim.y;
    const int qch = total >> 3, rch = total & 7;
    const int xcd = id & 7, ps = id >> 3;
    const int wg = (xcd < rch ? xcd*(qch+1) : rch*(qch+1) + (xcd-rch)*qch) + ps;
    const int m0 = (wg / gridDim.x) * 128, n0 = (wg % gridDim.x) * 128;

    const int rr = tid >> 3, chv = tid & 7;
    const int cxo = (chv ^ (rr & 7)) * 8;
    const u16* gA = A  + (size_t)(m0 + rr) * K + cxo;
    const u16* gB = BT + (size_t)(n0 + rr) * K + cxo;

    auto stageA = [&](int kk) {
        #pragma unroll
        for (int i=0;i<4;i++)
            __builtin_amdgcn_global_load_lds(
                (const __attribute__((address_space(1))) void*)(gA + (size_t)(i*32)*K + kk),
                (__attribute__((address_space(3))) void*)(&As[i*32 + wv*8][0]), 16, 0, 0);
    };
    auto stageB = [&](int kk) {
        #pragma unroll
        for (int i=0;i<4;i++)
            __builtin_amdgcn_global_load_lds(
                (const __attribute__((address_space(1))) void*)(gB + (size_t)(i*32)*K + kk),
                (__attribute__((address_space(3))) void*)(&Bs[i*32 + wv*8][0]), 16, 0, 0);
    };
    auto rdA = [&](int m, int ks)->bf16x8 {
        int r = wq*64 + m*16 + l15;
        return *(const bf16x8*)(&As[r][((ks*4 + g4) ^ (r & 7))*8]);
    };
    auto rdB = [&](int n, int ks)->bf16x8 {
        int r = wp*64 + n*16 + l15;
        return *(const bf16x8*)(&Bs[r][((ks*4 + g4) ^ (r & 7))*8]);
    };

    f32x4 acc[4][4];
    #pragma unroll
    for (int i=0;i<4;i++)
        #pragma unroll
        for (int j=0;j<4;j++) acc[i][j] = (f32x4){0.f,0.f,0.f,0.f};

    const int NT = K >> 6;
    for (int t = 0; t < NT; ++t) {
        stageA(t << 6); stageB(t << 6);
        __syncthreads();
        #pragma unroll
        for (int ks=0; ks<2; ++ks) {
            bf16x8 aF[4], bF[4];
            #pragma unroll
            for (int m=0;m<4;m++) aF[m] = rdA(m, ks);
            #pragma unroll
            for (int n=0;n<4;n++) bF[n] = rdB(n, ks);
            #pragma unroll
            for (int m=0;m<4;m++)
                #pragma unroll
                for (int n=0;n<4;n++)
                    acc[m][n] = __builtin_amdgcn_mfma_f32_16x16x32_bf16(aF[m], bF[n], acc[m][n], 0,0,0);
        }
        __syncthreads();
    }

    #pragma unroll
    for (int m=0;m<4;m++) {
        const int gr = m0 + wq*64 + m*16 + g4*4;
        #pragma unroll
        for (int n=0;n<4;n++) {
            const int gc = n0 + wp*64 + n*16 + l15;
            if (gc < Nreal) {
                #pragma unroll
                for (int r=0;r<4;r++) {
                    float vv = acc[m][n][r];
                    size_t oi = (size_t)(gr + r)*Nreal + gc;
                    if constexpr (EPI == 0) {
                        outb[oi] = f2bf(vv);
                    } else if constexpr (EPI == 1) {
                        outb[oi] = f2bf(gelu_f(vv + bias[gc]));
                    } else {
                        outf[oi] = outf[oi] + vv + bias[gc];
                    }
                }
            }
        }
    }
}

// ---- 256Mx128N GEMM + optional co-launched convT blocks for next layer ----
// blocks [0, gemmBlocks) do GEMM; blocks >= gemmBlocks do 64x64 convT tiles into narena.
template<int EPI>
__global__ __launch_bounds__(512, 4)
void gemm256_kernel(const u16* __restrict__ A, const u16* __restrict__ BT,
                    int K, int Nreal, u16* __restrict__ outb,
                    const float* __restrict__ bias,
                    int nxg, int gemmBlocks,
                    const float* __restrict__ nqkvw, const float* __restrict__ npw,
                    const float* __restrict__ nf1w, const float* __restrict__ nf2w,
                    u16* __restrict__ narena)
{
    __shared__ u16 As[256][64];   // 32 KiB
    __shared__ u16 Bs[128][64];   // 16 KiB
    const int bid = blockIdx.x;
    if (bid >= gemmBlocks) {
        // ---- convT tile for next layer (512 threads, 64x64 fp32 tile in As) ----
        float* tile = (float*)&As[0][0];          // 64*65 floats = 16.6 KB
        int id = bid - gemmBlocks;                // 0..3887
        const float* W; u16* WT; int K2, Nw, t0;
        if (id < 972)        { W = nqkvw; WT = narena;        K2 = DD;    Nw = TD;    t0 = id; }
        else if (id < 1296)  { W = npw;   WT = narena + OP_;  K2 = DD;    Nw = DD;    t0 = id - 972; }
        else if (id < 2592)  { W = nf1w;  WT = narena + OF1;  K2 = DD;    Nw = MLPD_; t0 = id - 1296; }
        else                 { W = nf2w;  WT = narena + OF2;  K2 = MLPD_; Nw = DD;    t0 = id - 2592; }
        int nx = Nw >> 6;
        int nb = (t0 % nx) * 64, kb = (t0 / nx) * 64;
        int tx = threadIdx.x & 63, ty = threadIdx.x >> 6;   // ty 0..7
        #pragma unroll
        for (int r=0;r<8;r++)
            tile[(r*8 + ty)*65 + tx] = W[(size_t)(kb + r*8 + ty)*Nw + nb + tx];
        __syncthreads();
        int j = threadIdx.x & 63, i2 = threadIdx.x >> 6;    // i2 0..7
        #pragma unroll
        for (int r=0;r<8;r++) {
            int n = i2 + r*8;
            WT[(size_t)(nb + n)*K2 + kb + j] = f2bf(tile[j*65 + n]);
        }
        return;
    }
    const int tid = threadIdx.x;
    const int lane = tid & 63, wv = tid >> 6;     // 8 waves
    const int wm = wv & 3, wn = wv >> 2;          // 4M x 2N
    const int l15 = lane & 15, g4 = lane >> 4;

    const int id = bid;
    const int total = gemmBlocks;
    const int qch = total >> 3, rch = total & 7;
    const int xcd = id & 7, ps = id >> 3;
    const int wg = (xcd < rch ? xcd*(qch+1) : rch*(qch+1) + (xcd-rch)*qch) + ps;
    const int m0 = (wg / nxg) * 256, n0 = (wg % nxg) * 128;

    const int rr = tid >> 3, chv = tid & 7;
    const int cxo = (chv ^ (rr & 7)) * 8;
    const u16* gA = A  + (size_t)(m0 + rr) * K + cxo;
    const u16* gB = BT + (size_t)(n0 + rr) * K + cxo;

    auto stageA = [&](int kk) {
        #pragma unroll
        for (int i=0;i<4;i++)
            __builtin_amdgcn_global_load_lds(
                (const __attribute__((address_space(1))) void*)(gA + (size_t)(i*64)*K + kk),
                (__attribute__((address_space(3))) void*)(&As[i*64 + wv*8][0]), 16, 0, 0);
    };
    auto stageB = [&](int kk) {
        #pragma unroll
        for (int i=0;i<2;i++)
            __builtin_amdgcn_global_load_lds(
                (const __attribute__((address_space(1))) void*)(gB + (size_t)(i*64)*K + kk),
                (__attribute__((address_space(3))) void*)(&Bs[i*64 + wv*8][0]), 16, 0, 0);
    };
    auto rdA = [&](int m, int ks)->bf16x8 {
        int r = wm*64 + m*16 + l15;
        return *(const bf16x8*)(&As[r][((ks*4 + g4) ^ (r & 7))*8]);
    };
    auto rdB = [&](int n, int ks)->bf16x8 {
        int r = wn*64 + n*16 + l15;
        return *(const bf16x8*)(&Bs[r][((ks*4 + g4) ^ (r & 7))*8]);
    };

    f32x4 acc[4][4];
    #pragma unroll
    for (int i=0;i<4;i++)
        #pragma unroll
        for (int j=0;j<4;j++) acc[i][j] = (f32x4){0.f,0.f,0.f,0.f};

    const int NT = K >> 6;
    for (int t = 0; t < NT; ++t) {
        stageA(t << 6); stageB(t << 6);
        __syncthreads();
        #pragma unroll
        for (int ks=0; ks<2; ++ks) {
            bf16x8 aF[4], bF[4];
            #pragma unroll
            for (int m=0;m<4;m++) aF[m] = rdA(m, ks);
            #pragma unroll
            for (int n=0;n<4;n++) bF[n] = rdB(n, ks);
            #pragma unroll
            for (int m=0;m<4;m++)
                #pragma unroll
                for (int n=0;n<4;n++)
                    acc[m][n] = __builtin_amdgcn_mfma_f32_16x16x32_bf16(aF[m], bF[n], acc[m][n], 0,0,0);
        }
        __syncthreads();
    }

    #pragma unroll
    for (int m=0;m<4;m++) {
        const int gr = m0 + wm*64 + m*16 + g4*4;
        #pragma unroll
        for (int n=0;n<4;n++) {
            const int gc = n0 + wn*64 + n*16 + l15;
            if (gc < Nreal) {
                #pragma unroll
                for (int r=0;r<4;r++) {
                    float vv = acc[m][n][r];
                    size_t oi = (size_t)(gr + r)*Nreal + gc;
                    if constexpr (EPI == 0) {
                        outb[oi] = f2bf(vv);
                    } else {
                        outb[oi] = f2bf(gelu_f(vv + bias[gc]));
                    }
                }
            }
        }
    }
}

// ---- merged: vtran (blocks 0..511) + qknorm (blocks 512..) ----
__global__ void qkvt_kernel(const u16* __restrict__ qkv,
                            const float* __restrict__ qg, const float* __restrict__ qb,
                            const float* __restrict__ kg, const float* __restrict__ kb,
                            u16* __restrict__ qn, u16* __restrict__ kn, u16* __restrict__ vt)
{
    __shared__ u16 tile[32][81];
    int id = blockIdx.x;
    if (id < 512) {
        int b = id; int h = b & 15, n = b >> 4;
        int tid = threadIdx.x;
        const size_t vbase = 2*DD + (size_t)h*HDIM;
        u16* vto = vt + (size_t)b * (HDV*LP);
        for (int lt = 0; lt < 9; ++lt) {
            #pragma unroll
            for (int e = 0; e < 9; ++e) {
                int ei = e*256 + tid;
                int r = ei / 72, c = ei - r*72;
                int l = lt*32 + r;
                u16 v = 0;
                if (l < LL) v = qkv[((size_t)n*LL + l)*TD + vbase + c];
                tile[r][c] = v;
            }
            __syncthreads();
            int j = tid & 31, hd0 = tid >> 5;
            #pragma unroll
            for (int e = 0; e < 10; ++e) {
                int hd = hd0 + e*8;
                u16 v = (hd < HDIM) ? tile[j][hd] : (u16)0;
                vto[(size_t)hd*LP + lt*32 + j] = v;
            }
            __syncthreads();
        }
        return;
    }
    int lane = threadIdx.x & 63, w = threadIdx.x >> 6;
    int s = lane & 15, g = lane >> 4;
    int idx = (id - 512)*16 + w*4 + g;
    int l = idx % LP; int nh = idx / LP;
    int h = nh & 15, n = nh >> 4;
    u32* qrow = (u32*)(qn + (size_t)idx * HDP);
    u32* krow = (u32*)(kn + (size_t)idx * HDP);
    if (l >= LL) {
        #pragma unroll
        for (int j=0;j<3;j++) { qrow[s + 16*j] = 0u; krow[s + 16*j] = 0u; }
        return;
    }
    size_t m = (size_t)n*LL + l;
    const u32* qs = (const u32*)(qkv + m*TD + h*HDIM);
    const u32* ks = (const u32*)(qkv + m*TD + DD + h*HDIM);

    float q0[3], q1[3], k0[3], k1[3];
    float sq = 0.f, sqq = 0.f, sk = 0.f, skk = 0.f;
    #pragma unroll
    for (int j=0;j<3;j++) {
        int c = s + 16*j;
        q0[j]=q1[j]=k0[j]=k1[j]=0.f;
        if (c < 36) {
            u32 uq = qs[c]; q0[j] = bf2f(uq & 0xffffu); q1[j] = bf2f(uq >> 16);
            u32 uk = ks[c]; k0[j] = bf2f(uk & 0xffffu); k1[j] = bf2f(uk >> 16);
        }
        sq += q0[j]+q1[j]; sqq += q0[j]*q0[j]+q1[j]*q1[j];
        sk += k0[j]+k1[j]; skk += k0[j]*k0[j]+k1[j]*k1[j];
    }
    sq = group16_sum(sq); sqq = group16_sum(sqq);
    sk = group16_sum(sk); skk = group16_sum(skk);
    float mq = sq*(1.f/HDIM), vq = sqq*(1.f/HDIM) - mq*mq, rq = rsqrtf(vq + 1e-5f);
    float mk = sk*(1.f/HDIM), vk = skk*(1.f/HDIM) - mk*mk, rk = rsqrtf(vk + 1e-5f);
    #pragma unroll
    for (int j=0;j<3;j++) {
        int c = s + 16*j;
        if (c < 36) {
            float o0 = ((q0[j]-mq)*rq*qg[c*2]   + qb[c*2]  ) * SCALE_;
            float o1 = ((q1[j]-mq)*rq*qg[c*2+1] + qb[c*2+1]) * SCALE_;
            qrow[c] = (u32)f2bf(o0) | ((u32)f2bf(o1) << 16);
            float p0 = (k0[j]-mk)*rk*kg[c*2]   + kb[c*2];
            float p1 = (k1[j]-mk)*rk*kg[c*2+1] + kb[c*2+1];
            krow[c] = (u32)f2bf(p0) | ((u32)f2bf(p1) << 16);
        } else {
            qrow[c] = 0u; krow[c] = 0u;
        }
    }
}

// ---- flash attention per (n,h); Q-tiles split over blockIdx.y (4-way) ----
__global__ __launch_bounds__(256)
void attn_kernel(const u16* __restrict__ qn, const u16* __restrict__ kn,
                 const u16* __restrict__ vt, u16* __restrict__ obuf)
{
    __shared__ u16 Pl[4][512];
    int b = blockIdx.x; int h = b & 15, n = b >> 4;
    int by = blockIdx.y;
    int lane = threadIdx.x & 63, w = threadIdx.x >> 6;
    const u16* qb_ = qn + (size_t)b * (LP*HDP);
    const u16* kb_ = kn + (size_t)b * (LP*HDP);
    const u16* vb_ = vt + (size_t)b * (HDV*LP);
    const int l15 = lane & 15, g4 = lane >> 4;
    const int slot = w + 4*by;    // 0..15

    for (int t = slot; t < 17; t += 16) {
        int qr0 = t*16;
        bf16x8 aq[3];
        #pragma unroll
        for (int fi=0; fi<3; ++fi)
            aq[fi] = *(const bf16x8*)(qb_ + (size_t)(qr0 + l15)*HDP + fi*32 + g4*8);
        f32x4 o[5];
        #pragma unroll
        for (int ht=0; ht<5; ++ht) o[ht] = (f32x4){0.f,0.f,0.f,0.f};
        float mrow[4], ssum[4];
        #pragma unroll
        for (int r=0;r<4;r++){ mrow[r] = -1e30f; ssum[r] = 0.f; }

        int umax = (qr0 + 15) >> 5;
        for (int u = 0; u <= umax; ++u) {
            f32x4 sacc[2];
            #pragma unroll
            for (int cc=0; cc<2; ++cc) {
                sacc[cc] = (f32x4){0.f,0.f,0.f,0.f};
                #pragma unroll
                for (int fi=0; fi<3; ++fi) {
                    bf16x8 bk = *(const bf16x8*)(kb_ + (size_t)(u*32 + cc*16 + l15)*HDP + fi*32 + g4*8);
                    sacc[cc] = __builtin_amdgcn_mfma_f32_16x16x32_bf16(aq[fi], bk, sacc[cc], 0,0,0);
                }
            }
            float pv0[4], pv1[4];
            #pragma unroll
            for (int r=0;r<4;r++) {
                int qi = qr0 + g4*4 + r;
                float s0 = ((u*32 + l15)      <= qi) ? sacc[0][r] : -1e30f;
                float s1 = ((u*32 + 16 + l15) <= qi) ? sacc[1][r] : -1e30f;
                float mx = fmaxf(s0, s1);
                mx = fmaxf(mx, __shfl_xor(mx, 1));
                mx = fmaxf(mx, __shfl_xor(mx, 2));
                mx = fmaxf(mx, __shfl_xor(mx, 4));
                mx = fmaxf(mx, __shfl_xor(mx, 8));
                float nm = fmaxf(mrow[r], mx);
                float sc = __expf(mrow[r] - nm);
                float p0 = __expf(s0 - nm), p1 = __expf(s1 - nm);
                float rsm = p0 + p1;
                rsm += __shfl_xor(rsm, 1); rsm += __shfl_xor(rsm, 2);
                rsm += __shfl_xor(rsm, 4); rsm += __shfl_xor(rsm, 8);
                ssum[r] = ssum[r]*sc + rsm;
                mrow[r] = nm;
                #pragma unroll
                for (int ht=0; ht<5; ++ht) o[ht][r] *= sc;
                pv0[r] = p0; pv1[r] = p1;
            }
            u16* pw_ = Pl[w];
            #pragma unroll
            for (int r=0;r<4;r++) {
                pw_[(g4*4+r)*32 + l15]      = f2bf(pv0[r]);
                pw_[(g4*4+r)*32 + 16 + l15] = f2bf(pv1[r]);
            }
            bf16x8 aP = *(const bf16x8*)(pw_ + l15*32 + g4*8);
            #pragma unroll
            for (int ht=0; ht<5; ++ht) {
                bf16x8 bv = *(const bf16x8*)(vb_ + (size_t)(ht*16 + l15)*LP + u*32 + g4*8);
                o[ht] = __builtin_amdgcn_mfma_f32_16x16x32_bf16(aP, bv, o[ht], 0,0,0);
            }
        }
        #pragma unroll
        for (int r=0;r<4;r++) {
            int l = qr0 + g4*4 + r;
            if (l < LL) {
                float inv = 1.f / ssum[r];
                size_t mro = ((size_t)n*LL + l)*DD + (size_t)h*HDIM;
                #pragma unroll
                for (int ht=0; ht<5; ++ht) {
                    int hd = ht*16 + l15;
                    if (hd < HDIM) obuf[mro + hd] = f2bf(o[ht][r] * inv);
                }
            }
        }
    }
}

// ---- final: LN + out projection ----
__global__ __launch_bounds__(256)
void outproj_kernel(const float* __restrict__ tokf, const float* __restrict__ g,
                    const float* __restrict__ b, const float* __restrict__ ow,
                    const float* __restrict__ ob, float* __restrict__ out)
{
    __shared__ float hrow[4][1152];
    int lane = threadIdx.x & 63, w = threadIdx.x >> 6;
    int idx = blockIdx.x*4 + w;
    int n = idx >> 8, p = idx & 255;
    size_t m = (size_t)n*LL + CT + p;
    const float* row = tokf + m*DD;
    float4 v[5];
    float s = 0.f, ss = 0.f;
    #pragma unroll
    for (int i=0;i<5;i++) {
        int id = i*64 + lane;
        if (id < 288) {
            v[i] = ((const float4*)row)[id];
            s  += v[i].x + v[i].y + v[i].z + v[i].w;
            ss += v[i].x*v[i].x + v[i].y*v[i].y + v[i].z*v[i].z + v[i].w*v[i].w;
        }
    }
    s = wave_sum64(s); ss = wave_sum64(ss);
    float mean = s*(1.f/DD), var = ss*(1.f/DD) - mean*mean;
    float rs = rsqrtf(var + 1e-5f);
    #pragma unroll
    for (int i=0;i<5;i++) {
        int id = i*64 + lane;
        if (id < 288) {
            int c0 = id*4;
            float4 gg = ((const float4*)g)[id];
            float4 bb = ((const float4*)b)[id];
            hrow[w][c0+0] = (v[i].x-mean)*rs*gg.x + bb.x;
            hrow[w][c0+1] = (v[i].y-mean)*rs*gg.y + bb.y;
            hrow[w][c0+2] = (v[i].z-mean)*rs*gg.z + bb.z;
            hrow[w][c0+3] = (v[i].w-mean)*rs*gg.w + bb.w;
        }
    }
    __syncthreads();
    int c = lane & 15, q = lane >> 4;
    float acc = 0.f;
    const float* hq = hrow[w] + q*288;
    const float* owq = ow + (size_t)(q*288)*16 + c;
    #pragma unroll 4
    for (int d = 0; d < 288; ++d)
        acc += hq[d] * owq[(size_t)d*16];
    acc += __shfl_xor(acc, 16);
    acc += __shfl_xor(acc, 32);
    if (lane < 16) {
        out[((size_t)n*PP + p)*PL_ + c] = acc + ob[c];
    }
}

extern "C" void kernel_launch(void* const* d_in, const int* in_sizes, int n_in,
                              void* d_out, int out_size, void* d_ws, size_t ws_size,
                              hipStream_t stream)
{
    const float* x    = (const float*)d_in[0];
    const float* t    = (const float*)d_in[1];
    const int*   y    = (const int*)d_in[2];
    const float* xw   = (const float*)d_in[3];
    const float* xb   = (const float*)d_in[4];
    const float* tw1  = (const float*)d_in[5];
    const float* tb1  = (const float*)d_in[6];
    const float* tw2  = (const float*)d_in[7];
    const float* tb2  = (const float*)d_in[8];
    const float* ytab = (const float*)d_in[9];
    const float* pos  = (const float*)d_in[10];
    const float* cpos = (const float*)d_in[11];
    const float* ln1g = (const float*)d_in[12];
    const float* ln1b = (const float*)d_in[13];
    const float* qkvw = (const float*)d_in[14];
    const float* qng  = (const float*)d_in[15];
    const float* qnbi = (const float*)d_in[16];
    const float* kng  = (const float*)d_in[17];
    const float* knbi = (const float*)d_in[18];
    const float* pw   = (const float*)d_in[19];
    const float* pb   = (const float*)d_in[20];
    const float* ln2g = (const float*)d_in[21];
    const float* ln2b = (const float*)d_in[22];
    const float* f1w  = (const float*)d_in[23];
    const float* f1b  = (const float*)d_in[24];
    const float* f2w  = (const float*)d_in[25];
    const float* f2b  = (const float*)d_in[26];
    const float* fng  = (const float*)d_in[27];
    const float* fnb  = (const float*)d_in[28];
    const float* ow   = (const float*)d_in[29];
    const float* ob   = (const float*)d_in[30];
    float* out = (float*)d_out;

    char* wsb = (char*)d_ws;
    size_t off = 0;
    auto alloc = [&](size_t bytes)->void* {
        void* p = wsb + off; off += (bytes + 255) & ~(size_t)255; return p;
    };
    float* tokf = (float*)alloc((size_t)MPAD*DD*4);
    u16*   hbuf = (u16*)  alloc((size_t)MPAD*DD*2);
    u16*   qkvb = (u16*)  alloc((size_t)MPAD*TD*2);
    u16*   qnb_ = (u16*)  alloc((size_t)BN_*HH*LP*HDP*2);
    u16*   knb_ = (u16*)  alloc((size_t)BN_*HH*LP*HDP*2);
    u16*   vtb  = (u16*)  alloc((size_t)BN_*HH*HDV*LP*2);
    u16*   obuf = (u16*)  alloc((size_t)MPAD*DD*2);
    u16*   mid  = (u16*)  alloc((size_t)MPAD*MLPD_*2);
    u16*   wT   = (u16*)  alloc((size_t)2*ARENA_ELEMS*2);   // double-buffered arena
    float* e1   = (float*)alloc((size_t)BN_*DD*4);
    float* te   = (float*)alloc((size_t)BN_*DD*4);
    (void)ws_size; (void)in_sizes; (void)n_in; (void)out_size;

    temb1_kernel<<<dim3(9,32),128,0,stream>>>(t, tw1, tb1, e1);
    temb2_kernel<<<dim3(9,32),128,0,stream>>>(e1, tw2, tb2, te);
    assemble_kernel<<<MPAD,256,0,stream>>>(x, y, xw, xb, ytab, pos, cpos, te, tokf);

    // layer-0 weights + ln1(0)
    convln_kernel<<<3888 + MPAD/4,256,0,stream>>>(qkvw, pw, f1w, f2w, wT,
                                                  tokf, ln1g, ln1b, hbuf);

    for (int L_ = 0; L_ < DEPTH_; ++L_) {
        u16* wa = wT + (size_t)(L_ & 1)*ARENA_ELEMS;
        u16* wn = wT + (size_t)((L_+1) & 1)*ARENA_ELEMS;
        gemm256_kernel<0><<<891,512,0,stream>>>(hbuf, wa, DD, TD, qkvb, nullptr,
                                                27, 891, nullptr, nullptr, nullptr, nullptr, nullptr);
        qkvt_kernel<<<512 + BN_*HH*LP/16,256,0,stream>>>(qkvb, qng + L_*HDIM, qnbi + L_*HDIM,
                                                         kng + L_*HDIM, knbi + L_*HDIM, qnb_, knb_, vtb);
        attn_kernel<<<dim3(BN_*HH, 4),256,0,stream>>>(qnb_, knb_, vtb, obuf);
        gemm97_kernel<2><<<dim3(9, 66),256,0,stream>>>(obuf, wa + OP_, DD, DD, nullptr, tokf, pb + L_*DD);
        ln_kernel<<<MPAD/4,256,0,stream>>>(tokf, ln2g + L_*DD, ln2b + L_*DD, hbuf);
        if (L_ < DEPTH_-1) {
            gemm256_kernel<1><<<1188 + 3888,512,0,stream>>>(hbuf, wa + OF1, DD, MLPD_, mid, f1b + L_*MLPD_,
                36, 1188,
                qkvw + (size_t)(L_+1)*DD*TD, pw + (size_t)(L_+1)*DD*DD,
                f1w + (size_t)(L_+1)*DD*MLPD_, f2w + (size_t)(L_+1)*MLPD_*DD, wn);
        } else {
            gemm256_kernel<1><<<1188,512,0,stream>>>(hbuf, wa + OF1, DD, MLPD_, mid, f1b + L_*MLPD_,
                36, 1188, nullptr, nullptr, nullptr, nullptr, nullptr);
        }
        gemm97_kernel<2><<<dim3(9, 66),256,0,stream>>>(mid, wa + OF2, MLPD_, DD, nullptr, tokf, f2b + L_*DD);
        if (L_ < DEPTH_-1)
            ln_kernel<<<MPAD/4,256,0,stream>>>(tokf, ln1g + (L_+1)*DD, ln1b + (L_+1)*DD, hbuf);
    }
    outproj_kernel<<<(BN_*PP)/4,256,0,stream>>>(tokf, fng, fnb, ow, ob, out);
}

// Round 17
// 5720.088 us; speedup vs baseline: 1.0058x; 1.0058x over previous
//
#include <hip/hip_runtime.h>
#include <hip/hip_bf16.h>
#include <cstdint>

#define DEV __device__ __forceinline__

typedef __attribute__((ext_vector_type(8))) short bf16x8;
typedef __attribute__((ext_vector_type(4))) float f32x4;
typedef unsigned short u16;
typedef unsigned int u32;

// ---- problem constants ----
constexpr int BN_   = 32;
constexpr int PP    = 256;
constexpr int PL_   = 16;
constexpr int CT    = 4;
constexpr int LL    = 260;
constexpr int DD    = 1152;
constexpr int HH    = 16;
constexpr int HDIM  = 72;
constexpr int DEPTH_= 12;
constexpr int TD    = 3456;
constexpr int MLPD_ = 4608;
constexpr int MREAL = BN_*LL;   // 8320
constexpr int MPAD  = 8448;     // 66*128 = 33*256
constexpr int LP    = 288;
constexpr int HDP   = 96;
constexpr int HDV   = 80;
constexpr float SCALE_ = 0.11785113019775793f;

// weight arena offsets (elements)
constexpr size_t OP_ = (size_t)TD*DD;
constexpr size_t OF1 = OP_ + (size_t)DD*DD;
constexpr size_t OF2 = OF1 + (size_t)MLPD_*DD;
constexpr size_t ARENA_ELEMS = OF2 + (size_t)1280*MLPD_;

DEV u16 f2bf(float f){
    union{float f; u32 i;} c; c.f = f;
    u32 u = c.i;
    u32 r = (u + 0x7fffu + ((u>>16)&1u)) >> 16;
    return (u16)r;
}
DEV float bf2f(u32 u){ union{u32 i; float f;} c; c.i = u<<16; return c.f; }

DEV float wave_sum64(float v){
    #pragma unroll
    for (int off=32; off; off>>=1) v += __shfl_xor(v, off);
    return v;
}
DEV float group16_sum(float v){
    #pragma unroll
    for (int off=8; off; off>>=1) v += __shfl_xor(v, off);
    return v;
}
DEV float gelu_f(float x){
    float u = 0.7978845608028654f * (x + 0.044715f * x*x*x);
    return x / (1.f + __expf(-2.f * u));
}

// ---- timestep embedding ----
__global__ void temb1_kernel(const float* __restrict__ t, const float* __restrict__ tw1,
                             const float* __restrict__ tb1, float* __restrict__ e1)
{
    int n = blockIdx.y, j = blockIdx.x*128 + threadIdx.x;
    float tv = t[n];
    float acc = tb1[j];
    const float k = 0.07195578415606394f;
    for (int i = 0; i < 128; ++i) {
        float f = __expf(-k * (float)i);
        float a = tv * f;
        float sa = sinf(a), ca = cosf(a);
        acc += ca * tw1[(size_t)i*DD + j] + sa * tw1[(size_t)(i+128)*DD + j];
    }
    e1[(size_t)n*DD + j] = acc / (1.f + __expf(-acc));
}

__global__ void temb2_kernel(const float* __restrict__ e1, const float* __restrict__ tw2,
                             const float* __restrict__ tb2, float* __restrict__ te)
{
    int n = blockIdx.y, j = blockIdx.x*128 + threadIdx.x;
    float acc = tb2[j];
    const float* er = e1 + (size_t)n*DD;
    for (int kk = 0; kk < DD; ++kk)
        acc += er[kk] * tw2[(size_t)kk*DD + j];
    te[(size_t)n*DD + j] = acc;
}

// ---- token assembly ----
__global__ void assemble_kernel(const float* __restrict__ x, const int* __restrict__ y,
                                const float* __restrict__ xw, const float* __restrict__ xb,
                                const float* __restrict__ ytab, const float* __restrict__ pos,
                                const float* __restrict__ cpos, const float* __restrict__ te,
                                float* __restrict__ tokf)
{
    int m = blockIdx.x;
    if (m >= MREAL) {
        for (int d = threadIdx.x; d < DD; d += 256) tokf[(size_t)m*DD + d] = 0.f;
        return;
    }
    int n = m / LL, l = m % LL;
    if (l < CT) {
        int cls = y[n];
        const float* yt = ytab + (size_t)cls*(CT*DD) + (size_t)l*DD;
        const float* cp = cpos + (size_t)l*DD;
        const float* tm = te + (size_t)n*DD;
        for (int d = threadIdx.x; d < DD; d += 256)
            tokf[(size_t)m*DD + d] = yt[d] + cp[d] + tm[d];
    } else {
        int p = l - CT;
        const float* xr = x + (size_t)(n*PP + p)*PL_;
        float xv[16];
        #pragma unroll
        for (int i=0;i<16;i++) xv[i] = xr[i];
        const float* pr = pos + (size_t)p*DD;
        for (int d = threadIdx.x; d < DD; d += 256) {
            float acc = xb[d] + pr[d];
            #pragma unroll
            for (int i=0;i<16;i++) acc += xv[i] * xw[(size_t)i*DD + d];
            tokf[(size_t)m*DD + d] = acc;
        }
    }
}

// ---- merged: convT4 (blocks 0..3887) + ln1 (blocks 3888..) ----
__global__ void convln_kernel(const float* __restrict__ qkvw, const float* __restrict__ pw,
                              const float* __restrict__ f1w, const float* __restrict__ f2w,
                              u16* __restrict__ arena,
                              const float* __restrict__ src, const float* __restrict__ g,
                              const float* __restrict__ b, u16* __restrict__ dst)
{
    __shared__ float tile[64][65];
    int id = blockIdx.x;
    if (id >= 3888) {
        int lane = threadIdx.x & 63, w = threadIdx.x >> 6;
        int m = (id - 3888)*4 + w;
        const float* row = src + (size_t)m * DD;
        float4 v[5];
        float s = 0.f, ss = 0.f;
        #pragma unroll
        for (int i=0;i<5;i++) {
            int idx = i*64 + lane;
            if (idx < 288) {
                v[i] = ((const float4*)row)[idx];
                s  += v[i].x + v[i].y + v[i].z + v[i].w;
                ss += v[i].x*v[i].x + v[i].y*v[i].y + v[i].z*v[i].z + v[i].w*v[i].w;
            }
        }
        s = wave_sum64(s); ss = wave_sum64(ss);
        float mean = s * (1.f/DD);
        float var  = ss * (1.f/DD) - mean*mean;
        float rs   = rsqrtf(var + 1e-5f);
        u16* orow = dst + (size_t)m*DD;
        #pragma unroll
        for (int i=0;i<5;i++) {
            int idx = i*64 + lane;
            if (idx < 288) {
                int c0 = idx*4;
                float4 gg = ((const float4*)g)[idx];
                float4 bb = ((const float4*)b)[idx];
                ushort4 o;
                o.x = f2bf((v[i].x-mean)*rs*gg.x + bb.x);
                o.y = f2bf((v[i].y-mean)*rs*gg.y + bb.y);
                o.z = f2bf((v[i].z-mean)*rs*gg.z + bb.z);
                o.w = f2bf((v[i].w-mean)*rs*gg.w + bb.w);
                *(ushort4*)(orow + c0) = o;
            }
        }
        return;
    }
    const float* W; u16* WT; int K, Nw, t0;
    if (id < 972)        { W = qkvw; WT = arena;        K = DD;    Nw = TD;    t0 = id; }
    else if (id < 1296)  { W = pw;   WT = arena + OP_;  K = DD;    Nw = DD;    t0 = id - 972; }
    else if (id < 2592)  { W = f1w;  WT = arena + OF1;  K = DD;    Nw = MLPD_; t0 = id - 1296; }
    else                 { W = f2w;  WT = arena + OF2;  K = MLPD_; Nw = DD;    t0 = id - 2592; }
    int nx = Nw >> 6;
    int nb = (t0 % nx) * 64, kb = (t0 / nx) * 64;
    int tx = threadIdx.x & 63, ty = threadIdx.x >> 6;
    #pragma unroll
    for (int r=0;r<16;r++)
        tile[r*4 + ty][tx] = W[(size_t)(kb + r*4 + ty)*Nw + nb + tx];
    __syncthreads();
    int j = threadIdx.x & 63, i2 = threadIdx.x >> 6;
    #pragma unroll
    for (int r=0;r<16;r++) {
        int n = i2 + r*4;
        WT[(size_t)(nb + n)*K + kb + j] = f2bf(tile[j][n]);
    }
}

// ---- LayerNorm (standalone, for ln2) ----
__global__ void ln_kernel(const float* __restrict__ src, const float* __restrict__ g,
                          const float* __restrict__ b, u16* __restrict__ dst)
{
    int lane = threadIdx.x & 63, w = threadIdx.x >> 6;
    int m = blockIdx.x*4 + w;
    const float* row = src + (size_t)m * DD;
    float4 v[5];
    float s = 0.f, ss = 0.f;
    #pragma unroll
    for (int i=0;i<5;i++) {
        int idx = i*64 + lane;
        if (idx < 288) {
            v[i] = ((const float4*)row)[idx];
            s  += v[i].x + v[i].y + v[i].z + v[i].w;
            ss += v[i].x*v[i].x + v[i].y*v[i].y + v[i].z*v[i].z + v[i].w*v[i].w;
        }
    }
    s = wave_sum64(s); ss = wave_sum64(ss);
    float mean = s * (1.f/DD);
    float var  = ss * (1.f/DD) - mean*mean;
    float rs   = rsqrtf(var + 1e-5f);
    u16* orow = dst + (size_t)m*DD;
    #pragma unroll
    for (int i=0;i<5;i++) {
        int idx = i*64 + lane;
        if (idx < 288) {
            int c0 = idx*4;
            float4 gg = ((const float4*)g)[idx];
            float4 bb = ((const float4*)b)[idx];
            ushort4 o;
            o.x = f2bf((v[i].x-mean)*rs*gg.x + bb.x);
            o.y = f2bf((v[i].y-mean)*rs*gg.y + bb.y);
            o.z = f2bf((v[i].z-mean)*rs*gg.z + bb.z);
            o.w = f2bf((v[i].w-mean)*rs*gg.w + bb.w);
            *(ushort4*)(orow + c0) = o;
        }
    }
}

// ---- m97-structure GEMM: 128x128, BK=64, single-buffer (proj/fc2) ----
// EPI: 0 = bf16 store, 1 = gelu(x+bias)->bf16, 2 = x + bias + tokf -> tokf fp32
template<int EPI>
__global__ __launch_bounds__(256, 4)
void gemm97_kernel(const u16* __restrict__ A, const u16* __restrict__ BT,
                   int K, int Nreal, u16* __restrict__ outb, float* __restrict__ outf,
                   const float* __restrict__ bias)
{
    __shared__ u16 As[128][64];
    __shared__ u16 Bs[128][64];
    const int tid = threadIdx.x;
    const int lane = tid & 63, wv = tid >> 6;
    const int wq = wv >> 1, wp = wv & 1;
    const int l15 = lane & 15, g4 = lane >> 4;

    const int id = blockIdx.x + gridDim.x * blockIdx.y;
    const int total = gridDim.x * gridDim.y;
    const int qch = total >> 3, rch = total & 7;
    const int xcd = id & 7, ps = id >> 3;
    const int wg = (xcd < rch ? xcd*(qch+1) : rch*(qch+1) + (xcd-rch)*qch) + ps;
    const int m0 = (wg / gridDim.x) * 128, n0 = (wg % gridDim.x) * 128;

    const int rr = tid >> 3, chv = tid & 7;
    const int cxo = (chv ^ (rr & 7)) * 8;
    const u16* gA = A  + (size_t)(m0 + rr) * K + cxo;
    const u16* gB = BT + (size_t)(n0 + rr) * K + cxo;

    auto stageA = [&](int kk) {
        #pragma unroll
        for (int i=0;i<4;i++)
            __builtin_amdgcn_global_load_lds(
                (const __attribute__((address_space(1))) void*)(gA + (size_t)(i*32)*K + kk),
                (__attribute__((address_space(3))) void*)(&As[i*32 + wv*8][0]), 16, 0, 0);
    };
    auto stageB = [&](int kk) {
        #pragma unroll
        for (int i=0;i<4;i++)
            __builtin_amdgcn_global_load_lds(
                (const __attribute__((address_space(1))) void*)(gB + (size_t)(i*32)*K + kk),
                (__attribute__((address_space(3))) void*)(&Bs[i*32 + wv*8][0]), 16, 0, 0);
    };
    auto rdA = [&](int m, int ks)->bf16x8 {
        int r = wq*64 + m*16 + l15;
        return *(const bf16x8*)(&As[r][((ks*4 + g4) ^ (r & 7))*8]);
    };
    auto rdB = [&](int n, int ks)->bf16x8 {
        int r = wp*64 + n*16 + l15;
        return *(const bf16x8*)(&Bs[r][((ks*4 + g4) ^ (r & 7))*8]);
    };

    f32x4 acc[4][4];
    #pragma unroll
    for (int i=0;i<4;i++)
        #pragma unroll
        for (int j=0;j<4;j++) acc[i][j] = (f32x4){0.f,0.f,0.f,0.f};

    const int NT = K >> 6;
    for (int t = 0; t < NT; ++t) {
        stageA(t << 6); stageB(t << 6);
        __syncthreads();
        #pragma unroll
        for (int ks=0; ks<2; ++ks) {
            bf16x8 aF[4], bF[4];
            #pragma unroll
            for (int m=0;m<4;m++) aF[m] = rdA(m, ks);
            #pragma unroll
            for (int n=0;n<4;n++) bF[n] = rdB(n, ks);
            #pragma unroll
            for (int m=0;m<4;m++)
                #pragma unroll
                for (int n=0;n<4;n++)
                    acc[m][n] = __builtin_amdgcn_mfma_f32_16x16x32_bf16(aF[m], bF[n], acc[m][n], 0,0,0);
        }
        __syncthreads();
    }

    #pragma unroll
    for (int m=0;m<4;m++) {
        const int gr = m0 + wq*64 + m*16 + g4*4;
        #pragma unroll
        for (int n=0;n<4;n++) {
            const int gc = n0 + wp*64 + n*16 + l15;
            if (gc < Nreal) {
                #pragma unroll
                for (int r=0;r<4;r++) {
                    float vv = acc[m][n][r];
                    size_t oi = (size_t)(gr + r)*Nreal + gc;
                    if constexpr (EPI == 0) {
                        outb[oi] = f2bf(vv);
                    } else if constexpr (EPI == 1) {
                        outb[oi] = f2bf(gelu_f(vv + bias[gc]));
                    } else {
                        outf[oi] = outf[oi] + vv + bias[gc];
                    }
                }
            }
        }
    }
}

// ---- 256Mx128N GEMM, BK=64, single-buffer 48KB, 8 waves (qkv/fc1) ----
template<int EPI>
__global__ __launch_bounds__(512, 4)
void gemm256_kernel(const u16* __restrict__ A, const u16* __restrict__ BT,
                    int K, int Nreal, u16* __restrict__ outb,
                    const float* __restrict__ bias)
{
    __shared__ u16 As[256][64];   // 32 KiB
    __shared__ u16 Bs[128][64];   // 16 KiB
    const int tid = threadIdx.x;
    const int lane = tid & 63, wv = tid >> 6;     // 8 waves
    const int wm = wv & 3, wn = wv >> 2;          // 4M x 2N
    const int l15 = lane & 15, g4 = lane >> 4;

    const int id = blockIdx.x + gridDim.x * blockIdx.y;
    const int total = gridDim.x * gridDim.y;
    const int qch = total >> 3, rch = total & 7;
    const int xcd = id & 7, ps = id >> 3;
    const int wg = (xcd < rch ? xcd*(qch+1) : rch*(qch+1) + (xcd-rch)*qch) + ps;
    const int m0 = (wg / gridDim.x) * 256, n0 = (wg % gridDim.x) * 128;

    const int rr = tid >> 3, chv = tid & 7;
    const int cxo = (chv ^ (rr & 7)) * 8;
    const u16* gA = A  + (size_t)(m0 + rr) * K + cxo;
    const u16* gB = BT + (size_t)(n0 + rr) * K + cxo;

    auto stageA = [&](int kk) {
        #pragma unroll
        for (int i=0;i<4;i++)
            __builtin_amdgcn_global_load_lds(
                (const __attribute__((address_space(1))) void*)(gA + (size_t)(i*64)*K + kk),
                (__attribute__((address_space(3))) void*)(&As[i*64 + wv*8][0]), 16, 0, 0);
    };
    auto stageB = [&](int kk) {
        #pragma unroll
        for (int i=0;i<2;i++)
            __builtin_amdgcn_global_load_lds(
                (const __attribute__((address_space(1))) void*)(gB + (size_t)(i*64)*K + kk),
                (__attribute__((address_space(3))) void*)(&Bs[i*64 + wv*8][0]), 16, 0, 0);
    };
    auto rdA = [&](int m, int ks)->bf16x8 {
        int r = wm*64 + m*16 + l15;
        return *(const bf16x8*)(&As[r][((ks*4 + g4) ^ (r & 7))*8]);
    };
    auto rdB = [&](int n, int ks)->bf16x8 {
        int r = wn*64 + n*16 + l15;
        return *(const bf16x8*)(&Bs[r][((ks*4 + g4) ^ (r & 7))*8]);
    };

    f32x4 acc[4][4];
    #pragma unroll
    for (int i=0;i<4;i++)
        #pragma unroll
        for (int j=0;j<4;j++) acc[i][j] = (f32x4){0.f,0.f,0.f,0.f};

    const int NT = K >> 6;
    for (int t = 0; t < NT; ++t) {
        stageA(t << 6); stageB(t << 6);
        __syncthreads();
        #pragma unroll
        for (int ks=0; ks<2; ++ks) {
            bf16x8 aF[4], bF[4];
            #pragma unroll
            for (int m=0;m<4;m++) aF[m] = rdA(m, ks);
            #pragma unroll
            for (int n=0;n<4;n++) bF[n] = rdB(n, ks);
            #pragma unroll
            for (int m=0;m<4;m++)
                #pragma unroll
                for (int n=0;n<4;n++)
                    acc[m][n] = __builtin_amdgcn_mfma_f32_16x16x32_bf16(aF[m], bF[n], acc[m][n], 0,0,0);
        }
        __syncthreads();
    }

    #pragma unroll
    for (int m=0;m<4;m++) {
        const int gr = m0 + wm*64 + m*16 + g4*4;
        #pragma unroll
        for (int n=0;n<4;n++) {
            const int gc = n0 + wn*64 + n*16 + l15;
            if (gc < Nreal) {
                #pragma unroll
                for (int r=0;r<4;r++) {
                    float vv = acc[m][n][r];
                    size_t oi = (size_t)(gr + r)*Nreal + gc;
                    if constexpr (EPI == 0) {
                        outb[oi] = f2bf(vv);
                    } else {
                        outb[oi] = f2bf(gelu_f(vv + bias[gc]));
                    }
                }
            }
        }
    }
}

// ---- merged: vtran (blocks 0..511) + qknorm (blocks 512..) ----
__global__ void qkvt_kernel(const u16* __restrict__ qkv,
                            const float* __restrict__ qg, const float* __restrict__ qb,
                            const float* __restrict__ kg, const float* __restrict__ kb,
                            u16* __restrict__ qn, u16* __restrict__ kn, u16* __restrict__ vt)
{
    __shared__ u16 tile[32][81];
    int id = blockIdx.x;
    if (id < 512) {
        int b = id; int h = b & 15, n = b >> 4;
        int tid = threadIdx.x;
        const size_t vbase = 2*DD + (size_t)h*HDIM;
        u16* vto = vt + (size_t)b * (HDV*LP);
        for (int lt = 0; lt < 9; ++lt) {
            #pragma unroll
            for (int e = 0; e < 9; ++e) {
                int ei = e*256 + tid;
                int r = ei / 72, c = ei - r*72;
                int l = lt*32 + r;
                u16 v = 0;
                if (l < LL) v = qkv[((size_t)n*LL + l)*TD + vbase + c];
                tile[r][c] = v;
            }
            __syncthreads();
            int j = tid & 31, hd0 = tid >> 5;
            #pragma unroll
            for (int e = 0; e < 10; ++e) {
                int hd = hd0 + e*8;
                u16 v = (hd < HDIM) ? tile[j][hd] : (u16)0;
                vto[(size_t)hd*LP + lt*32 + j] = v;
            }
            __syncthreads();
        }
        return;
    }
    int lane = threadIdx.x & 63, w = threadIdx.x >> 6;
    int s = lane & 15, g = lane >> 4;
    int idx = (id - 512)*16 + w*4 + g;
    int l = idx % LP; int nh = idx / LP;
    int h = nh & 15, n = nh >> 4;
    u32* qrow = (u32*)(qn + (size_t)idx * HDP);
    u32* krow = (u32*)(kn + (size_t)idx * HDP);
    if (l >= LL) {
        #pragma unroll
        for (int j=0;j<3;j++) { qrow[s + 16*j] = 0u; krow[s + 16*j] = 0u; }
        return;
    }
    size_t m = (size_t)n*LL + l;
    const u32* qs = (const u32*)(qkv + m*TD + h*HDIM);
    const u32* ks = (const u32*)(qkv + m*TD + DD + h*HDIM);

    float q0[3], q1[3], k0[3], k1[3];
    float sq = 0.f, sqq = 0.f, sk = 0.f, skk = 0.f;
    #pragma unroll
    for (int j=0;j<3;j++) {
        int c = s + 16*j;
        q0[j]=q1[j]=k0[j]=k1[j]=0.f;
        if (c < 36) {
            u32 uq = qs[c]; q0[j] = bf2f(uq & 0xffffu); q1[j] = bf2f(uq >> 16);
            u32 uk = ks[c]; k0[j] = bf2f(uk & 0xffffu); k1[j] = bf2f(uk >> 16);
        }
        sq += q0[j]+q1[j]; sqq += q0[j]*q0[j]+q1[j]*q1[j];
        sk += k0[j]+k1[j]; skk += k0[j]*k0[j]+k1[j]*k1[j];
    }
    sq = group16_sum(sq); sqq = group16_sum(sqq);
    sk = group16_sum(sk); skk = group16_sum(skk);
    float mq = sq*(1.f/HDIM), vq = sqq*(1.f/HDIM) - mq*mq, rq = rsqrtf(vq + 1e-5f);
    float mk = sk*(1.f/HDIM), vk = skk*(1.f/HDIM) - mk*mk, rk = rsqrtf(vk + 1e-5f);
    #pragma unroll
    for (int j=0;j<3;j++) {
        int c = s + 16*j;
        if (c < 36) {
            float o0 = ((q0[j]-mq)*rq*qg[c*2]   + qb[c*2]  ) * SCALE_;
            float o1 = ((q1[j]-mq)*rq*qg[c*2+1] + qb[c*2+1]) * SCALE_;
            qrow[c] = (u32)f2bf(o0) | ((u32)f2bf(o1) << 16);
            float p0 = (k0[j]-mk)*rk*kg[c*2]   + kb[c*2];
            float p1 = (k1[j]-mk)*rk*kg[c*2+1] + kb[c*2+1];
            krow[c] = (u32)f2bf(p0) | ((u32)f2bf(p1) << 16);
        } else {
            qrow[c] = 0u; krow[c] = 0u;
        }
    }
}

// ---- flash attention per (n,h); Q-tiles split over blockIdx.y (4-way) ----
__global__ __launch_bounds__(256)
void attn_kernel(const u16* __restrict__ qn, const u16* __restrict__ kn,
                 const u16* __restrict__ vt, u16* __restrict__ obuf)
{
    __shared__ u16 Pl[4][512];
    int b = blockIdx.x; int h = b & 15, n = b >> 4;
    int by = blockIdx.y;
    int lane = threadIdx.x & 63, w = threadIdx.x >> 6;
    const u16* qb_ = qn + (size_t)b * (LP*HDP);
    const u16* kb_ = kn + (size_t)b * (LP*HDP);
    const u16* vb_ = vt + (size_t)b * (HDV*LP);
    const int l15 = lane & 15, g4 = lane >> 4;
    const int slot = w + 4*by;    // 0..15

    for (int t = slot; t < 17; t += 16) {
        int qr0 = t*16;
        bf16x8 aq[3];
        #pragma unroll
        for (int fi=0; fi<3; ++fi)
            aq[fi] = *(const bf16x8*)(qb_ + (size_t)(qr0 + l15)*HDP + fi*32 + g4*8);
        f32x4 o[5];
        #pragma unroll
        for (int ht=0; ht<5; ++ht) o[ht] = (f32x4){0.f,0.f,0.f,0.f};
        float mrow[4], ssum[4];
        #pragma unroll
        for (int r=0;r<4;r++){ mrow[r] = -1e30f; ssum[r] = 0.f; }

        int umax = (qr0 + 15) >> 5;
        for (int u = 0; u <= umax; ++u) {
            f32x4 sacc[2];
            #pragma unroll
            for (int cc=0; cc<2; ++cc) {
                sacc[cc] = (f32x4){0.f,0.f,0.f,0.f};
                #pragma unroll
                for (int fi=0; fi<3; ++fi) {
                    bf16x8 bk = *(const bf16x8*)(kb_ + (size_t)(u*32 + cc*16 + l15)*HDP + fi*32 + g4*8);
                    sacc[cc] = __builtin_amdgcn_mfma_f32_16x16x32_bf16(aq[fi], bk, sacc[cc], 0,0,0);
                }
            }
            float pv0[4], pv1[4];
            #pragma unroll
            for (int r=0;r<4;r++) {
                int qi = qr0 + g4*4 + r;
                float s0 = ((u*32 + l15)      <= qi) ? sacc[0][r] : -1e30f;
                float s1 = ((u*32 + 16 + l15) <= qi) ? sacc[1][r] : -1e30f;
                float mx = fmaxf(s0, s1);
                mx = fmaxf(mx, __shfl_xor(mx, 1));
                mx = fmaxf(mx, __shfl_xor(mx, 2));
                mx = fmaxf(mx, __shfl_xor(mx, 4));
                mx = fmaxf(mx, __shfl_xor(mx, 8));
                float nm = fmaxf(mrow[r], mx);
                float sc = __expf(mrow[r] - nm);
                float p0 = __expf(s0 - nm), p1 = __expf(s1 - nm);
                float rsm = p0 + p1;
                rsm += __shfl_xor(rsm, 1); rsm += __shfl_xor(rsm, 2);
                rsm += __shfl_xor(rsm, 4); rsm += __shfl_xor(rsm, 8);
                ssum[r] = ssum[r]*sc + rsm;
                mrow[r] = nm;
                #pragma unroll
                for (int ht=0; ht<5; ++ht) o[ht][r] *= sc;
                pv0[r] = p0; pv1[r] = p1;
            }
            u16* pw_ = Pl[w];
            #pragma unroll
            for (int r=0;r<4;r++) {
                pw_[(g4*4+r)*32 + l15]      = f2bf(pv0[r]);
                pw_[(g4*4+r)*32 + 16 + l15] = f2bf(pv1[r]);
            }
            bf16x8 aP = *(const bf16x8*)(pw_ + l15*32 + g4*8);
            #pragma unroll
            for (int ht=0; ht<5; ++ht) {
                bf16x8 bv = *(const bf16x8*)(vb_ + (size_t)(ht*16 + l15)*LP + u*32 + g4*8);
                o[ht] = __builtin_amdgcn_mfma_f32_16x16x32_bf16(aP, bv, o[ht], 0,0,0);
            }
        }
        #pragma unroll
        for (int r=0;r<4;r++) {
            int l = qr0 + g4*4 + r;
            if (l < LL) {
                float inv = 1.f / ssum[r];
                size_t mro = ((size_t)n*LL + l)*DD + (size_t)h*HDIM;
                #pragma unroll
                for (int ht=0; ht<5; ++ht) {
                    int hd = ht*16 + l15;
                    if (hd < HDIM) obuf[mro + hd] = f2bf(o[ht][r] * inv);
                }
            }
        }
    }
}

// ---- final: LN + out projection ----
__global__ __launch_bounds__(256)
void outproj_kernel(const float* __restrict__ tokf, const float* __restrict__ g,
                    const float* __restrict__ b, const float* __restrict__ ow,
                    const float* __restrict__ ob, float* __restrict__ out)
{
    __shared__ float hrow[4][1152];
    int lane = threadIdx.x & 63, w = threadIdx.x >> 6;
    int idx = blockIdx.x*4 + w;
    int n = idx >> 8, p = idx & 255;
    size_t m = (size_t)n*LL + CT + p;
    const float* row = tokf + m*DD;
    float4 v[5];
    float s = 0.f, ss = 0.f;
    #pragma unroll
    for (int i=0;i<5;i++) {
        int id = i*64 + lane;
        if (id < 288) {
            v[i] = ((const float4*)row)[id];
            s  += v[i].x + v[i].y + v[i].z + v[i].w;
            ss += v[i].x*v[i].x + v[i].y*v[i].y + v[i].z*v[i].z + v[i].w*v[i].w;
        }
    }
    s = wave_sum64(s); ss = wave_sum64(ss);
    float mean = s*(1.f/DD), var = ss*(1.f/DD) - mean*mean;
    float rs = rsqrtf(var + 1e-5f);
    #pragma unroll
    for (int i=0;i<5;i++) {
        int id = i*64 + lane;
        if (id < 288) {
            int c0 = id*4;
            float4 gg = ((const float4*)g)[id];
            float4 bb = ((const float4*)b)[id];
            hrow[w][c0+0] = (v[i].x-mean)*rs*gg.x + bb.x;
            hrow[w][c0+1] = (v[i].y-mean)*rs*gg.y + bb.y;
            hrow[w][c0+2] = (v[i].z-mean)*rs*gg.z + bb.z;
            hrow[w][c0+3] = (v[i].w-mean)*rs*gg.w + bb.w;
        }
    }
    __syncthreads();
    int c = lane & 15, q = lane >> 4;
    float acc = 0.f;
    const float* hq = hrow[w] + q*288;
    const float* owq = ow + (size_t)(q*288)*16 + c;
    #pragma unroll 4
    for (int d = 0; d < 288; ++d)
        acc += hq[d] * owq[(size_t)d*16];
    acc += __shfl_xor(acc, 16);
    acc += __shfl_xor(acc, 32);
    if (lane < 16) {
        out[((size_t)n*PP + p)*PL_ + c] = acc + ob[c];
    }
}

extern "C" void kernel_launch(void* const* d_in, const int* in_sizes, int n_in,
                              void* d_out, int out_size, void* d_ws, size_t ws_size,
                              hipStream_t stream)
{
    const float* x    = (const float*)d_in[0];
    const float* t    = (const float*)d_in[1];
    const int*   y    = (const int*)d_in[2];
    const float* xw   = (const float*)d_in[3];
    const float* xb   = (const float*)d_in[4];
    const float* tw1  = (const float*)d_in[5];
    const float* tb1  = (const float*)d_in[6];
    const float* tw2  = (const float*)d_in[7];
    const float* tb2  = (const float*)d_in[8];
    const float* ytab = (const float*)d_in[9];
    const float* pos  = (const float*)d_in[10];
    const float* cpos = (const float*)d_in[11];
    const float* ln1g = (const float*)d_in[12];
    const float* ln1b = (const float*)d_in[13];
    const float* qkvw = (const float*)d_in[14];
    const float* qng  = (const float*)d_in[15];
    const float* qnbi = (const float*)d_in[16];
    const float* kng  = (const float*)d_in[17];
    const float* knbi = (const float*)d_in[18];
    const float* pw   = (const float*)d_in[19];
    const float* pb   = (const float*)d_in[20];
    const float* ln2g = (const float*)d_in[21];
    const float* ln2b = (const float*)d_in[22];
    const float* f1w  = (const float*)d_in[23];
    const float* f1b  = (const float*)d_in[24];
    const float* f2w  = (const float*)d_in[25];
    const float* f2b  = (const float*)d_in[26];
    const float* fng  = (const float*)d_in[27];
    const float* fnb  = (const float*)d_in[28];
    const float* ow   = (const float*)d_in[29];
    const float* ob   = (const float*)d_in[30];
    float* out = (float*)d_out;

    char* wsb = (char*)d_ws;
    size_t off = 0;
    auto alloc = [&](size_t bytes)->void* {
        void* p = wsb + off; off += (bytes + 255) & ~(size_t)255; return p;
    };
    float* tokf = (float*)alloc((size_t)MPAD*DD*4);
    u16*   hbuf = (u16*)  alloc((size_t)MPAD*DD*2);
    u16*   qkvb = (u16*)  alloc((size_t)MPAD*TD*2);
    u16*   qnb_ = (u16*)  alloc((size_t)BN_*HH*LP*HDP*2);
    u16*   knb_ = (u16*)  alloc((size_t)BN_*HH*LP*HDP*2);
    u16*   vtb  = (u16*)  alloc((size_t)BN_*HH*HDV*LP*2);
    u16*   obuf = (u16*)  alloc((size_t)MPAD*DD*2);
    u16*   mid  = (u16*)  alloc((size_t)MPAD*MLPD_*2);
    u16*   wT   = (u16*)  alloc(ARENA_ELEMS*2);
    float* e1   = (float*)alloc((size_t)BN_*DD*4);
    float* te   = (float*)alloc((size_t)BN_*DD*4);
    (void)ws_size; (void)in_sizes; (void)n_in; (void)out_size;

    temb1_kernel<<<dim3(9,32),128,0,stream>>>(t, tw1, tb1, e1);
    temb2_kernel<<<dim3(9,32),128,0,stream>>>(e1, tw2, tb2, te);
    assemble_kernel<<<MPAD,256,0,stream>>>(x, y, xw, xb, ytab, pos, cpos, te, tokf);

    for (int L_ = 0; L_ < DEPTH_; ++L_) {
        convln_kernel<<<3888 + MPAD/4,256,0,stream>>>(qkvw + (size_t)L_*DD*TD, pw + (size_t)L_*DD*DD,
                                                      f1w + (size_t)L_*DD*MLPD_, f2w + (size_t)L_*MLPD_*DD,
                                                      wT, tokf, ln1g + L_*DD, ln1b + L_*DD, hbuf);
        gemm256_kernel<0><<<dim3(27, 33),512,0,stream>>>(hbuf, wT, DD, TD, qkvb, nullptr);
        qkvt_kernel<<<512 + BN_*HH*LP/16,256,0,stream>>>(qkvb, qng + L_*HDIM, qnbi + L_*HDIM,
                                                         kng + L_*HDIM, knbi + L_*HDIM, qnb_, knb_, vtb);
        attn_kernel<<<dim3(BN_*HH, 4),256,0,stream>>>(qnb_, knb_, vtb, obuf);
        gemm97_kernel<2><<<dim3(9, 66),256,0,stream>>>(obuf, wT + OP_, DD, DD, nullptr, tokf, pb + L_*DD);
        ln_kernel<<<MPAD/4,256,0,stream>>>(tokf, ln2g + L_*DD, ln2b + L_*DD, hbuf);
        gemm256_kernel<1><<<dim3(36, 33),512,0,stream>>>(hbuf, wT + OF1, DD, MLPD_, mid, f1b + L_*MLPD_);
        gemm97_kernel<2><<<dim3(9, 66),256,0,stream>>>(mid, wT + OF2, MLPD_, DD, nullptr, tokf, f2b + L_*DD);
    }
    outproj_kernel<<<(BN_*PP)/4,256,0,stream>>>(tokf, fng, fnb, ow, ob, out);
}